// Round 2
// baseline (2866.346 us; speedup 1.0000x reference)
//
#include <hip/hip_runtime.h>
#include <hip/hip_bf16.h>

typedef unsigned short u16;
typedef __bf16 bf16x8 __attribute__((ext_vector_type(8)));
typedef float  f32x4  __attribute__((ext_vector_type(4)));

constexpr int TT = 4096;   // seq
constexpr int BBATCH = 2;  // batch
constexpr int EE = 1024;   // embed
constexpr int HH = 16;     // heads
constexpr int DD = 64;     // head dim
constexpr int WQ = 256;    // one-sided window
constexpr int GG = 64;     // global tokens

// ---------- bf16 helpers ----------
__device__ __forceinline__ float bf2f(u16 u) {
    union { unsigned int i; float f; } c; c.i = ((unsigned int)u) << 16; return c.f;
}
__device__ __forceinline__ float bfl(unsigned int u) {
    union { unsigned int i; float f; } c; c.i = u << 16; return c.f;
}
__device__ __forceinline__ float bfh(unsigned int u) {
    union { unsigned int i; float f; } c; c.i = u & 0xffff0000u; return c.f;
}
__device__ __forceinline__ u16 f2bf(float f) {
    union { float f; unsigned int i; } c; c.f = f;
    unsigned int x = c.i;
    return (u16)((x + 0x7fffu + ((x >> 16) & 1u)) >> 16);  // RNE
}
__device__ __forceinline__ uint4 pack8(float4 a, float4 b) {
    uint4 r;
    r.x = (unsigned)f2bf(a.x) | ((unsigned)f2bf(a.y) << 16);
    r.y = (unsigned)f2bf(a.z) | ((unsigned)f2bf(a.w) << 16);
    r.z = (unsigned)f2bf(b.x) | ((unsigned)f2bf(b.y) << 16);
    r.w = (unsigned)f2bf(b.z) | ((unsigned)f2bf(b.w) << 16);
    return r;
}
__device__ __forceinline__ float dot8(uint4 u, const float* qq) {
    float s;
    s = qq[0] * bfl(u.x);
    s = fmaf(qq[1], bfh(u.x), s);
    s = fmaf(qq[2], bfl(u.y), s);
    s = fmaf(qq[3], bfh(u.y), s);
    s = fmaf(qq[4], bfl(u.z), s);
    s = fmaf(qq[5], bfh(u.z), s);
    s = fmaf(qq[6], bfl(u.w), s);
    s = fmaf(qq[7], bfh(u.w), s);
    return s;
}

// ---------- GEMM: C = (A @ W^T + bias) * scale ----------
// A fp32 (A_BF16=0) or bf16 (A_BF16=1); W,bias fp32; C bf16 (C_F32=0) or fp32 (C_F32=1).
// fp32 operands are converted to bf16 (RNE) during LDS staging; MFMA bf16, fp32 accum.
// permA_S/permC_S >= 0 maps logical row m to source/dst row (m & (2^S-1))*2 + (m >> S)
// (i.e. [R,B=2,*] <-> [B=2,R,*]). Tile 128x128, BK=32, 4 waves (2x2), 256 thr.
template<int A_BF16, int C_F32>
__global__ __launch_bounds__(256) void gemm_kernel(
    const void* __restrict__ Av, const float* __restrict__ W,
    const float* __restrict__ bias, void* __restrict__ Cv,
    int N, int K, float scale, int permA_S, int permC_S)
{
    const int tid  = threadIdx.x;
    const int lane = tid & 63;
    const int wave = tid >> 6;
    const int wm = wave >> 1, wn = wave & 1;
    const int m0 = blockIdx.y << 7, n0 = blockIdx.x << 7;

    __shared__ __align__(16) u16 As[128][40];   // pad 32->40: 80B row stride (16B-aligned)
    __shared__ __align__(16) u16 Bs[128][40];

    const int srow = tid >> 2;            // 0..63
    const int scol = (tid & 3) << 3;      // element col 0,8,16,24
    auto mapr = [](int r, int s) -> size_t {
        return (s >= 0) ? (size_t)((r & ((1 << s) - 1)) * BBATCH + (r >> s)) : (size_t)r;
    };
    const size_t ar0 = mapr(m0 + srow, permA_S), ar1 = mapr(m0 + srow + 64, permA_S);
    const u16*   aB0 = (const u16*)Av + ar0 * K + scol;
    const u16*   aB1 = (const u16*)Av + ar1 * K + scol;
    const float* aF0 = (const float*)Av + ar0 * K + scol;
    const float* aF1 = (const float*)Av + ar1 * K + scol;
    const float* wF0 = W + (size_t)(n0 + srow) * K + scol;
    const float* wF1 = wF0 + (size_t)64 * K;
    u16* ldsA0 = &As[srow][scol];
    u16* ldsA1 = &As[srow + 64][scol];
    u16* ldsB0 = &Bs[srow][scol];
    u16* ldsB1 = &Bs[srow + 64][scol];

    f32x4 acc[4][4];
#pragma unroll
    for (int i = 0; i < 4; i++)
#pragma unroll
        for (int j = 0; j < 4; j++)
            acc[i][j] = (f32x4){0.f, 0.f, 0.f, 0.f};

    const int fr = lane & 15;            // fragment row/col within 16
    const int fq = (lane >> 4) << 3;     // k offset = quad*8

    for (int k0 = 0; k0 < K; k0 += 32) {
        uint4 a0, a1;
        if (A_BF16) {
            a0 = *(const uint4*)(aB0 + k0);
            a1 = *(const uint4*)(aB1 + k0);
        } else {
            a0 = pack8(*(const float4*)(aF0 + k0), *(const float4*)(aF0 + k0 + 4));
            a1 = pack8(*(const float4*)(aF1 + k0), *(const float4*)(aF1 + k0 + 4));
        }
        const uint4 b0 = pack8(*(const float4*)(wF0 + k0), *(const float4*)(wF0 + k0 + 4));
        const uint4 b1 = pack8(*(const float4*)(wF1 + k0), *(const float4*)(wF1 + k0 + 4));
        *(uint4*)ldsA0 = a0;
        *(uint4*)ldsA1 = a1;
        *(uint4*)ldsB0 = b0;
        *(uint4*)ldsB1 = b1;
        __syncthreads();
        bf16x8 af[4], bfv[4];
#pragma unroll
        for (int i = 0; i < 4; i++)
            af[i] = *(const bf16x8*)&As[(wm << 6) + (i << 4) + fr][fq];
#pragma unroll
        for (int j = 0; j < 4; j++)
            bfv[j] = *(const bf16x8*)&Bs[(wn << 6) + (j << 4) + fr][fq];
#pragma unroll
        for (int i = 0; i < 4; i++)
#pragma unroll
            for (int j = 0; j < 4; j++)
                acc[i][j] = __builtin_amdgcn_mfma_f32_16x16x32_bf16(af[i], bfv[j], acc[i][j], 0, 0, 0);
        __syncthreads();
    }

    // epilogue: D row = quad*4 + r, col = lane&15
    const int colbase = n0 + (wn << 6);
    const int rowbase = m0 + (wm << 6) + ((lane >> 4) << 2);
#pragma unroll
    for (int j = 0; j < 4; j++) {
        const int col = colbase + (j << 4) + fr;
        const float bv = bias[col];
#pragma unroll
        for (int i = 0; i < 4; i++) {
#pragma unroll
            for (int r = 0; r < 4; r++) {
                const int row = rowbase + (i << 4) + r;
                const float val = (acc[i][j][r] + bv) * scale;
                const size_t dst = mapr(row, permC_S) * N + col;
                if (C_F32) ((float*)Cv)[dst] = val;
                else       ((u16*)Cv)[dst]   = f2bf(val);
            }
        }
    }
}

// ---------- band (sliding-window + global-key) attention ----------
// one wave per (b,h,t); scores = [64 global | 513 band], softmax, PV. q,k,v,attnb bf16 [B,T,H*D].
__global__ __launch_bounds__(256) void band_attn_kernel(
    const u16* __restrict__ q, const u16* __restrict__ k, const u16* __restrict__ v,
    u16* __restrict__ attnb)
{
    const int tid = threadIdx.x, lane = tid & 63, w = tid >> 6;
    const int gi = blockIdx.x * 4 + w;          // (b*H + h)*T + t
    const int t  = gi & (TT - 1);
    const int bh = gi >> 12;
    const int h  = bh & (HH - 1);
    const int b  = bh >> 4;

    __shared__ __align__(16) float Ps[4][580];
    float* P = Ps[w];

    const size_t baseK = (size_t)b * TT * EE + (size_t)h * DD;

    // q row -> 64 registers
    float qr[64];
    {
        const uint4* qp = (const uint4*)(q + baseK + (size_t)t * EE);
#pragma unroll
        for (int i = 0; i < 8; i++) {
            uint4 u = qp[i];
            qr[i * 8 + 0] = bfl(u.x); qr[i * 8 + 1] = bfh(u.x);
            qr[i * 8 + 2] = bfl(u.y); qr[i * 8 + 3] = bfh(u.y);
            qr[i * 8 + 4] = bfl(u.z); qr[i * 8 + 5] = bfh(u.z);
            qr[i * 8 + 6] = bfl(u.w); qr[i * 8 + 7] = bfh(u.w);
        }
    }

    // scores: idx<64 -> global key idx; else band slot j=idx-64, pos = t - W + j
#pragma unroll 1
    for (int c = 0; c < 10; c++) {
        const int idx = (c << 6) + lane;
        const int pos = (idx < GG) ? idx : (t + idx - (WQ + GG));
        const bool ok = (idx < GG) || ((idx < GG + 2 * WQ + 1) && pos >= 0 && pos < TT);
        const int posc = ok ? pos : 0;
        const uint4* kp = (const uint4*)(k + baseK + (size_t)posc * EE);
        float s = 0.f;
#pragma unroll
        for (int i = 0; i < 8; i++) s += dot8(kp[i], &qr[i * 8]);
        if (idx < GG + 2 * WQ + 1) P[idx] = ok ? s : -1e30f;
    }
    __syncthreads();

    float mx = -1e30f;
    for (int i = lane; i < 577; i += 64) mx = fmaxf(mx, P[i]);
#pragma unroll
    for (int off = 32; off; off >>= 1) mx = fmaxf(mx, __shfl_xor(mx, off));
    float sum = 0.f;
    for (int i = lane; i < 577; i += 64) { float e = __expf(P[i] - mx); P[i] = e; sum += e; }
#pragma unroll
    for (int off = 32; off; off >>= 1) sum += __shfl_xor(sum, off);
    if (lane < 3) P[577 + lane] = 0.f;   // pad for float4 PV loop
    const float inv = 1.f / sum;
    __syncthreads();

    // PV: lane owns dim d=lane
    float acc = 0.f;
    const u16* vb = v + baseK + lane;
#pragma unroll 1
    for (int i0 = 0; i0 < 580; i0 += 4) {
        const float4 p4 = *(const float4*)&P[i0];
#pragma unroll
        for (int u = 0; u < 4; u++) {
            const int i = i0 + u;
            int pos = (i < GG) ? i : (t + i - (WQ + GG));
            pos = pos < 0 ? 0 : (pos > TT - 1 ? TT - 1 : pos);   // clamped; p==0 for invalid
            const float pw = (&p4.x)[u];
            acc = fmaf(pw, bf2f(vb[(size_t)pos * EE]), acc);
        }
    }
    acc *= inv;
    attnb[baseK + (size_t)t * EE + lane] = f2bf(acc);
}

// ---------- global-token attention: rows t < G attend ALL keys with *_global projections ----------
// one block (256 thr) per (b,g,h)
__global__ __launch_bounds__(256) void global_attn_kernel(
    const u16* __restrict__ qg, const u16* __restrict__ kg, const u16* __restrict__ vg,
    u16* __restrict__ attnb)
{
    const int tid = threadIdx.x, lane = tid & 63, w = tid >> 6;
    const int h  = blockIdx.x & (HH - 1);
    const int bg = blockIdx.x >> 4;
    const int g  = bg & (GG - 1);
    const int b  = bg >> 6;

    __shared__ float S[TT];        // 16 KB scores
    __shared__ float red[4];
    __shared__ float pacc[4][64];

    const size_t baseK = (size_t)b * TT * EE + (size_t)h * DD;

    float qr[64];
    {
        const uint4* qp = (const uint4*)(qg + ((size_t)(b * GG + g) * EE + (size_t)h * DD));
#pragma unroll
        for (int i = 0; i < 8; i++) {
            uint4 u = qp[i];
            qr[i * 8 + 0] = bfl(u.x); qr[i * 8 + 1] = bfh(u.x);
            qr[i * 8 + 2] = bfl(u.y); qr[i * 8 + 3] = bfh(u.y);
            qr[i * 8 + 4] = bfl(u.z); qr[i * 8 + 5] = bfh(u.z);
            qr[i * 8 + 6] = bfl(u.w); qr[i * 8 + 7] = bfh(u.w);
        }
    }

#pragma unroll 1
    for (int i = 0; i < TT / 256; i++) {
        const int key = tid + (i << 8);
        const uint4* kp = (const uint4*)(kg + baseK + (size_t)key * EE);
        float s = 0.f;
#pragma unroll
        for (int j = 0; j < 8; j++) s += dot8(kp[j], &qr[j * 8]);
        S[key] = s;
    }
    __syncthreads();

    float mx = -1e30f;
    for (int i = tid; i < TT; i += 256) mx = fmaxf(mx, S[i]);
#pragma unroll
    for (int off = 32; off; off >>= 1) mx = fmaxf(mx, __shfl_xor(mx, off));
    if (lane == 0) red[w] = mx;
    __syncthreads();
    mx = fmaxf(fmaxf(red[0], red[1]), fmaxf(red[2], red[3]));
    __syncthreads();

    float sum = 0.f;
    for (int i = tid; i < TT; i += 256) { float e = __expf(S[i] - mx); S[i] = e; sum += e; }
#pragma unroll
    for (int off = 32; off; off >>= 1) sum += __shfl_xor(sum, off);
    if (lane == 0) red[w] = sum;
    __syncthreads();
    const float tot = red[0] + red[1] + red[2] + red[3];

    // PV: wave w handles keys w, w+4, ...; lane owns dim d=lane
    float acc = 0.f;
#pragma unroll 1
    for (int key = w; key < TT; key += 4)
        acc = fmaf(S[key], bf2f(vg[baseK + (size_t)key * EE + lane]), acc);
    pacc[w][lane] = acc;
    __syncthreads();
    if (tid < 64) {
        const float r = (pacc[0][tid] + pacc[1][tid] + pacc[2][tid] + pacc[3][tid]) / tot;
        attnb[baseK + (size_t)g * EE + tid] = f2bf(r);
    }
}

extern "C" void kernel_launch(void* const* d_in, const int* in_sizes, int n_in,
                              void* d_out, int out_size, void* d_ws, size_t ws_size,
                              hipStream_t stream)
{
    (void)in_sizes; (void)n_in; (void)out_size; (void)ws_size;
    const float* query = (const float*)d_in[0];
    // d_in[1] = attn_mask (unused by reference)
    const float* Wq  = (const float*)d_in[2];  const float* bq  = (const float*)d_in[3];
    const float* Wk  = (const float*)d_in[4];  const float* bk  = (const float*)d_in[5];
    const float* Wv  = (const float*)d_in[6];  const float* bv  = (const float*)d_in[7];
    const float* Wqg = (const float*)d_in[8];  const float* bqg = (const float*)d_in[9];
    const float* Wkg = (const float*)d_in[10]; const float* bkg = (const float*)d_in[11];
    const float* Wvg = (const float*)d_in[12]; const float* bvg = (const float*)d_in[13];
    const float* Wo  = (const float*)d_in[14]; const float* bo  = (const float*)d_in[15];

    const size_t nfull = (size_t)BBATCH * TT * EE;   // 8.39M elems
    u16* q     = (u16*)d_ws;
    u16* k     = q  + nfull;
    u16* v     = k  + nfull;
    u16* kg    = v  + nfull;
    u16* vg    = kg + nfull;
    u16* qg    = vg + nfull;
    u16* attnb = qg + (size_t)BBATCH * GG * EE;
    // total ws: ~113 MB (bf16 intermediates)

    const dim3 blk(256);
    const dim3 gFull(EE / 128, (BBATCH * TT) / 128);
    const dim3 gQg(EE / 128, (BBATCH * GG) / 128);
    const float sc = 0.125f;  // D^-0.5
    const int ST = 12;        // log2(T), perm [T,B]<->[B,T]
    const int SG = 6;         // log2(G)

    // projections (x = query permuted [B,T,E]); fp32 in -> bf16 out
    gemm_kernel<0,0><<<gFull, blk, 0, stream>>>(query, Wq,  bq,  q,  EE, EE, sc,  ST, -1);
    gemm_kernel<0,0><<<gFull, blk, 0, stream>>>(query, Wk,  bk,  k,  EE, EE, 1.f, ST, -1);
    gemm_kernel<0,0><<<gFull, blk, 0, stream>>>(query, Wv,  bv,  v,  EE, EE, 1.f, ST, -1);
    gemm_kernel<0,0><<<gFull, blk, 0, stream>>>(query, Wkg, bkg, kg, EE, EE, 1.f, ST, -1);
    gemm_kernel<0,0><<<gFull, blk, 0, stream>>>(query, Wvg, bvg, vg, EE, EE, 1.f, ST, -1);
    gemm_kernel<0,0><<<gQg,   blk, 0, stream>>>(query, Wqg, bqg, qg, EE, EE, sc,  SG, -1);

    // attention
    band_attn_kernel<<<(BBATCH * HH * TT) / 4, blk, 0, stream>>>(q, k, v, attnb);
    global_attn_kernel<<<BBATCH * GG * HH, blk, 0, stream>>>(qg, kg, vg, attnb);

    // output projection: bf16 A -> fp32 out, store [B,T,E] -> [T,B,E]
    gemm_kernel<1,1><<<gFull, blk, 0, stream>>>(attnb, Wo, bo, (void*)d_out, EE, EE, 1.f, -1, ST);
}

// Round 3
// 1132.759 us; speedup vs baseline: 2.5304x; 2.5304x over previous
//
#include <hip/hip_runtime.h>
#include <hip/hip_bf16.h>

typedef unsigned short u16;
typedef __bf16 bf16x8 __attribute__((ext_vector_type(8)));
typedef float  f32x4  __attribute__((ext_vector_type(4)));

constexpr int TT = 4096;   // seq
constexpr int BBATCH = 2;  // batch
constexpr int EE = 1024;   // embed
constexpr int HH = 16;     // heads
constexpr int DD = 64;     // head dim
constexpr int WQ = 256;    // one-sided window
constexpr int GG = 64;     // global tokens

// ---------- bf16 helpers ----------
__device__ __forceinline__ float bf2f(u16 u) {
    union { unsigned int i; float f; } c; c.i = ((unsigned int)u) << 16; return c.f;
}
__device__ __forceinline__ float bfl(unsigned int u) {
    union { unsigned int i; float f; } c; c.i = u << 16; return c.f;
}
__device__ __forceinline__ float bfh(unsigned int u) {
    union { unsigned int i; float f; } c; c.i = u & 0xffff0000u; return c.f;
}
__device__ __forceinline__ u16 f2bf(float f) {
    union { float f; unsigned int i; } c; c.f = f;
    unsigned int x = c.i;
    return (u16)((x + 0x7fffu + ((x >> 16) & 1u)) >> 16);  // RNE
}
__device__ __forceinline__ uint4 pack8(float4 a, float4 b) {
    uint4 r;
    r.x = (unsigned)f2bf(a.x) | ((unsigned)f2bf(a.y) << 16);
    r.y = (unsigned)f2bf(a.z) | ((unsigned)f2bf(a.w) << 16);
    r.z = (unsigned)f2bf(b.x) | ((unsigned)f2bf(b.y) << 16);
    r.w = (unsigned)f2bf(b.z) | ((unsigned)f2bf(b.w) << 16);
    return r;
}
__device__ __forceinline__ float dot8(uint4 u, const float* qq) {
    float s;
    s = qq[0] * bfl(u.x);
    s = fmaf(qq[1], bfh(u.x), s);
    s = fmaf(qq[2], bfl(u.y), s);
    s = fmaf(qq[3], bfh(u.y), s);
    s = fmaf(qq[4], bfl(u.z), s);
    s = fmaf(qq[5], bfh(u.z), s);
    s = fmaf(qq[6], bfl(u.w), s);
    s = fmaf(qq[7], bfh(u.w), s);
    return s;
}

// ---------- GEMM: C = (A @ W^T + bias) * scale ----------
// (unchanged from round 2 — passed)
template<int A_BF16, int C_F32>
__global__ __launch_bounds__(256) void gemm_kernel(
    const void* __restrict__ Av, const float* __restrict__ W,
    const float* __restrict__ bias, void* __restrict__ Cv,
    int N, int K, float scale, int permA_S, int permC_S)
{
    const int tid  = threadIdx.x;
    const int lane = tid & 63;
    const int wave = tid >> 6;
    const int wm = wave >> 1, wn = wave & 1;
    const int m0 = blockIdx.y << 7, n0 = blockIdx.x << 7;

    __shared__ __align__(16) u16 As[128][40];
    __shared__ __align__(16) u16 Bs[128][40];

    const int srow = tid >> 2;
    const int scol = (tid & 3) << 3;
    auto mapr = [](int r, int s) -> size_t {
        return (s >= 0) ? (size_t)((r & ((1 << s) - 1)) * BBATCH + (r >> s)) : (size_t)r;
    };
    const size_t ar0 = mapr(m0 + srow, permA_S), ar1 = mapr(m0 + srow + 64, permA_S);
    const u16*   aB0 = (const u16*)Av + ar0 * K + scol;
    const u16*   aB1 = (const u16*)Av + ar1 * K + scol;
    const float* aF0 = (const float*)Av + ar0 * K + scol;
    const float* aF1 = (const float*)Av + ar1 * K + scol;
    const float* wF0 = W + (size_t)(n0 + srow) * K + scol;
    const float* wF1 = wF0 + (size_t)64 * K;
    u16* ldsA0 = &As[srow][scol];
    u16* ldsA1 = &As[srow + 64][scol];
    u16* ldsB0 = &Bs[srow][scol];
    u16* ldsB1 = &Bs[srow + 64][scol];

    f32x4 acc[4][4];
#pragma unroll
    for (int i = 0; i < 4; i++)
#pragma unroll
        for (int j = 0; j < 4; j++)
            acc[i][j] = (f32x4){0.f, 0.f, 0.f, 0.f};

    const int fr = lane & 15;
    const int fq = (lane >> 4) << 3;

    for (int k0 = 0; k0 < K; k0 += 32) {
        uint4 a0, a1;
        if (A_BF16) {
            a0 = *(const uint4*)(aB0 + k0);
            a1 = *(const uint4*)(aB1 + k0);
        } else {
            a0 = pack8(*(const float4*)(aF0 + k0), *(const float4*)(aF0 + k0 + 4));
            a1 = pack8(*(const float4*)(aF1 + k0), *(const float4*)(aF1 + k0 + 4));
        }
        const uint4 b0 = pack8(*(const float4*)(wF0 + k0), *(const float4*)(wF0 + k0 + 4));
        const uint4 b1 = pack8(*(const float4*)(wF1 + k0), *(const float4*)(wF1 + k0 + 4));
        *(uint4*)ldsA0 = a0;
        *(uint4*)ldsA1 = a1;
        *(uint4*)ldsB0 = b0;
        *(uint4*)ldsB1 = b1;
        __syncthreads();
        bf16x8 af[4], bfv[4];
#pragma unroll
        for (int i = 0; i < 4; i++)
            af[i] = *(const bf16x8*)&As[(wm << 6) + (i << 4) + fr][fq];
#pragma unroll
        for (int j = 0; j < 4; j++)
            bfv[j] = *(const bf16x8*)&Bs[(wn << 6) + (j << 4) + fr][fq];
#pragma unroll
        for (int i = 0; i < 4; i++)
#pragma unroll
            for (int j = 0; j < 4; j++)
                acc[i][j] = __builtin_amdgcn_mfma_f32_16x16x32_bf16(af[i], bfv[j], acc[i][j], 0, 0, 0);
        __syncthreads();
    }

    const int colbase = n0 + (wn << 6);
    const int rowbase = m0 + (wm << 6) + ((lane >> 4) << 2);
#pragma unroll
    for (int j = 0; j < 4; j++) {
        const int col = colbase + (j << 4) + fr;
        const float bv = bias[col];
#pragma unroll
        for (int i = 0; i < 4; i++) {
#pragma unroll
            for (int r = 0; r < 4; r++) {
                const int row = rowbase + (i << 4) + r;
                const float val = (acc[i][j][r] + bv) * scale;
                const size_t dst = mapr(row, permC_S) * N + col;
                if (C_F32) ((float*)Cv)[dst] = val;
                else       ((u16*)Cv)[dst]   = f2bf(val);
            }
        }
    }
}

// ---------- band attention, MFMA flash style ----------
// Block = (b, h, 64-query tile t0). 4 waves x 16 rows. 10 key-chunks of 64:
// chunk 0 = global keys [0,64) (always valid -> matches reference double-count);
// chunks 1..9 = band range [t0-256, t0+320), masked to |pos-t|<=W and 0<=pos<T.
// Online softmax; P via LDS round-trip (C-layout -> A-layout); V B-frags via
// scalar u16 reads from [key][dim] LDS (stride 70 elems = 35 banks, odd -> 2-way free).
__global__ __launch_bounds__(256) void band_attn_kernel(
    const u16* __restrict__ q, const u16* __restrict__ k, const u16* __restrict__ v,
    u16* __restrict__ attnb)
{
    const int tid  = threadIdx.x;
    const int lane = tid & 63;
    const int w    = tid >> 6;           // wave 0..3
    const int col  = lane & 15;
    const int quad = lane >> 4;

    const int qt = blockIdx.x & 63;            // query tile (fastest -> L2 slab locality)
    const int h  = (blockIdx.x >> 6) & (HH - 1);
    const int b  = blockIdx.x >> 10;
    const int t0 = qt << 6;

    __shared__ __align__(16) u16 Qs[64][72];
    __shared__ __align__(16) u16 Ks[64][72];
    __shared__ __align__(16) u16 Vs[64][70];
    __shared__ __align__(16) u16 Ps[4][16][72];

    const size_t base = (size_t)b * TT * EE + (size_t)h * DD;

    // ---- stage Q tile (once) ----
    {
        const int qr   = tid >> 2;            // 0..63
        const int part = (tid & 3) << 4;      // dim 0,16,32,48
        const uint4* src = (const uint4*)(q + base + (size_t)(t0 + qr) * EE + part);
        *(uint4*)&Qs[qr][part]     = src[0];
        *(uint4*)&Qs[qr][part + 8] = src[1];
    }

    float m_i[4], l_i[4];
    f32x4 acc_o[4];
#pragma unroll
    for (int r = 0; r < 4; r++) { m_i[r] = -1e30f; l_i[r] = 0.f; }
#pragma unroll
    for (int nt = 0; nt < 4; nt++) acc_o[nt] = (f32x4){0.f, 0.f, 0.f, 0.f};

#pragma unroll 1
    for (int cc = 0; cc < 10; cc++) {
        // ---- stage K,V chunk (64 keys x 64 dims) ----
        {
            const int kk   = tid >> 2;
            const int part = (tid & 3) << 4;
            int pos = (cc == 0) ? kk : (t0 - WQ + ((cc - 1) << 6) + kk);
            pos = pos < 0 ? 0 : (pos > TT - 1 ? TT - 1 : pos);
            const uint4* ks = (const uint4*)(k + base + (size_t)pos * EE + part);
            const uint4* vs = (const uint4*)(v + base + (size_t)pos * EE + part);
            const uint4 k0v = ks[0], k1v = ks[1];
            const uint4 v0v = vs[0], v1v = vs[1];
            *(uint4*)&Ks[kk][part]     = k0v;
            *(uint4*)&Ks[kk][part + 8] = k1v;
            // Vs rows are 4B-aligned only (stride 140B) -> b32 stores
            unsigned int* vd = (unsigned int*)&Vs[kk][part];
            vd[0] = v0v.x; vd[1] = v0v.y; vd[2] = v0v.z; vd[3] = v0v.w;
            vd[4] = v1v.x; vd[5] = v1v.y; vd[6] = v1v.z; vd[7] = v1v.w;
        }
        __syncthreads();

        // ---- QK^T: S (16 rows x 64 keys) ----
        bf16x8 qf0 = *(const bf16x8*)&Qs[(w << 4) + col][quad << 3];
        bf16x8 qf1 = *(const bf16x8*)&Qs[(w << 4) + col][32 + (quad << 3)];
        f32x4 acc_s[4];
#pragma unroll
        for (int nt = 0; nt < 4; nt++) {
            bf16x8 kf0 = *(const bf16x8*)&Ks[(nt << 4) + col][quad << 3];
            bf16x8 kf1 = *(const bf16x8*)&Ks[(nt << 4) + col][32 + (quad << 3)];
            f32x4 s = (f32x4){0.f, 0.f, 0.f, 0.f};
            s = __builtin_amdgcn_mfma_f32_16x16x32_bf16(qf0, kf0, s, 0, 0, 0);
            s = __builtin_amdgcn_mfma_f32_16x16x32_bf16(qf1, kf1, s, 0, 0, 0);
            acc_s[nt] = s;
        }

        // ---- mask band chunks ----
        if (cc > 0) {
            const int kj0 = (cc - 1) << 6;
#pragma unroll
            for (int nt = 0; nt < 4; nt++) {
#pragma unroll
                for (int r = 0; r < 4; r++) {
                    const int jp   = kj0 + (nt << 4) + col;     // 0..575 within band range
                    const int qrow = (w << 4) + (quad << 2) + r; // 0..63 within block
                    const int pos  = t0 - WQ + jp;
                    const bool ok  = (jp >= qrow) && (jp - qrow <= 2 * WQ) &&
                                     (pos >= 0) && (pos < TT);
                    if (!ok) acc_s[nt][r] = -1e30f;
                }
            }
        }

        // ---- online softmax ----
        float m_c[4], p_sum[4];
#pragma unroll
        for (int r = 0; r < 4; r++) {
            float mx = fmaxf(fmaxf(acc_s[0][r], acc_s[1][r]), fmaxf(acc_s[2][r], acc_s[3][r]));
#pragma unroll
            for (int off = 1; off < 16; off <<= 1) mx = fmaxf(mx, __shfl_xor(mx, off));
            m_c[r] = mx;
        }
#pragma unroll
        for (int r = 0; r < 4; r++) {
            const float m_new = fmaxf(m_i[r], m_c[r]);
            const float alpha = __expf(m_i[r] - m_new);
            m_i[r] = m_new;
            l_i[r] *= alpha;
#pragma unroll
            for (int nt = 0; nt < 4; nt++) acc_o[nt][r] *= alpha;
            float ps = 0.f;
#pragma unroll
            for (int nt = 0; nt < 4; nt++) {
                const float e = __expf(acc_s[nt][r] - m_new);
                acc_s[nt][r] = e;
                ps += e;
            }
            p_sum[r] = ps;
        }
#pragma unroll
        for (int r = 0; r < 4; r++) {
            float ps = p_sum[r];
#pragma unroll
            for (int off = 1; off < 16; off <<= 1) ps += __shfl_xor(ps, off);
            l_i[r] += ps;
        }

        // ---- P: C-layout regs -> LDS (A-layout readable) ----
#pragma unroll
        for (int nt = 0; nt < 4; nt++)
#pragma unroll
            for (int r = 0; r < 4; r++)
                Ps[w][(quad << 2) + r][(nt << 4) + col] = f2bf(acc_s[nt][r]);

        // ---- PV: O += P (16x64) @ V (64x64) ----
        bf16x8 pf0 = *(const bf16x8*)&Ps[w][col][quad << 3];
        bf16x8 pf1 = *(const bf16x8*)&Ps[w][col][32 + (quad << 3)];
#pragma unroll
        for (int nt = 0; nt < 4; nt++) {
            union { bf16x8 v; u16 e[8]; } vf0, vf1;
#pragma unroll
            for (int j = 0; j < 8; j++) {
                vf0.e[j] = Vs[(quad << 3) + j][(nt << 4) + col];
                vf1.e[j] = Vs[32 + (quad << 3) + j][(nt << 4) + col];
            }
            acc_o[nt] = __builtin_amdgcn_mfma_f32_16x16x32_bf16(pf0, vf0.v, acc_o[nt], 0, 0, 0);
            acc_o[nt] = __builtin_amdgcn_mfma_f32_16x16x32_bf16(pf1, vf1.v, acc_o[nt], 0, 0, 0);
        }
        __syncthreads();
    }

    // ---- epilogue: normalize, store bf16 ----
    float inv[4];
#pragma unroll
    for (int r = 0; r < 4; r++) inv[r] = 1.f / l_i[r];
#pragma unroll
    for (int nt = 0; nt < 4; nt++) {
#pragma unroll
        for (int r = 0; r < 4; r++) {
            const int t = t0 + (w << 4) + (quad << 2) + r;
            attnb[base + (size_t)t * EE + (nt << 4) + col] = f2bf(acc_o[nt][r] * inv[r]);
        }
    }
}

// ---------- global-token attention: rows t < G attend ALL keys ----------
// one block (256 thr) per (b,h,g); g fastest-varying for L2 slab locality.
__global__ __launch_bounds__(256) void global_attn_kernel(
    const u16* __restrict__ qg, const u16* __restrict__ kg, const u16* __restrict__ vg,
    u16* __restrict__ attnb)
{
    const int tid = threadIdx.x, lane = tid & 63, w = tid >> 6;
    const int g  = blockIdx.x & (GG - 1);
    const int h  = (blockIdx.x >> 6) & (HH - 1);
    const int b  = blockIdx.x >> 10;

    __shared__ float S[TT];
    __shared__ float red[4];
    __shared__ float pacc[4][64];

    const size_t baseK = (size_t)b * TT * EE + (size_t)h * DD;

    float qr[64];
    {
        const uint4* qp = (const uint4*)(qg + ((size_t)(b * GG + g) * EE + (size_t)h * DD));
#pragma unroll
        for (int i = 0; i < 8; i++) {
            uint4 u = qp[i];
            qr[i * 8 + 0] = bfl(u.x); qr[i * 8 + 1] = bfh(u.x);
            qr[i * 8 + 2] = bfl(u.y); qr[i * 8 + 3] = bfh(u.y);
            qr[i * 8 + 4] = bfl(u.z); qr[i * 8 + 5] = bfh(u.z);
            qr[i * 8 + 6] = bfl(u.w); qr[i * 8 + 7] = bfh(u.w);
        }
    }

#pragma unroll 1
    for (int i = 0; i < TT / 256; i++) {
        const int key = tid + (i << 8);
        const uint4* kp = (const uint4*)(kg + baseK + (size_t)key * EE);
        float s = 0.f;
#pragma unroll
        for (int j = 0; j < 8; j++) s += dot8(kp[j], &qr[j * 8]);
        S[key] = s;
    }
    __syncthreads();

    float mx = -1e30f;
    for (int i = tid; i < TT; i += 256) mx = fmaxf(mx, S[i]);
#pragma unroll
    for (int off = 32; off; off >>= 1) mx = fmaxf(mx, __shfl_xor(mx, off));
    if (lane == 0) red[w] = mx;
    __syncthreads();
    mx = fmaxf(fmaxf(red[0], red[1]), fmaxf(red[2], red[3]));
    __syncthreads();

    float sum = 0.f;
    for (int i = tid; i < TT; i += 256) { float e = __expf(S[i] - mx); S[i] = e; sum += e; }
#pragma unroll
    for (int off = 32; off; off >>= 1) sum += __shfl_xor(sum, off);
    if (lane == 0) red[w] = sum;
    __syncthreads();
    const float tot = red[0] + red[1] + red[2] + red[3];

    float acc = 0.f;
#pragma unroll 1
    for (int key = w; key < TT; key += 4)
        acc = fmaf(S[key], bf2f(vg[baseK + (size_t)key * EE + lane]), acc);
    pacc[w][lane] = acc;
    __syncthreads();
    if (tid < 64) {
        const float r = (pacc[0][tid] + pacc[1][tid] + pacc[2][tid] + pacc[3][tid]) / tot;
        attnb[baseK + (size_t)g * EE + tid] = f2bf(r);
    }
}

extern "C" void kernel_launch(void* const* d_in, const int* in_sizes, int n_in,
                              void* d_out, int out_size, void* d_ws, size_t ws_size,
                              hipStream_t stream)
{
    (void)in_sizes; (void)n_in; (void)out_size; (void)ws_size;
    const float* query = (const float*)d_in[0];
    const float* Wq  = (const float*)d_in[2];  const float* bq  = (const float*)d_in[3];
    const float* Wk  = (const float*)d_in[4];  const float* bk  = (const float*)d_in[5];
    const float* Wv  = (const float*)d_in[6];  const float* bv  = (const float*)d_in[7];
    const float* Wqg = (const float*)d_in[8];  const float* bqg = (const float*)d_in[9];
    const float* Wkg = (const float*)d_in[10]; const float* bkg = (const float*)d_in[11];
    const float* Wvg = (const float*)d_in[12]; const float* bvg = (const float*)d_in[13];
    const float* Wo  = (const float*)d_in[14]; const float* bo  = (const float*)d_in[15];

    const size_t nfull = (size_t)BBATCH * TT * EE;
    u16* q     = (u16*)d_ws;
    u16* k     = q  + nfull;
    u16* v     = k  + nfull;
    u16* kg    = v  + nfull;
    u16* vg    = kg + nfull;
    u16* qg    = vg + nfull;
    u16* attnb = qg + (size_t)BBATCH * GG * EE;

    const dim3 blk(256);
    const dim3 gFull(EE / 128, (BBATCH * TT) / 128);
    const dim3 gQg(EE / 128, (BBATCH * GG) / 128);
    const float sc = 0.125f;  // D^-0.5
    const int ST = 12;
    const int SG = 6;

    gemm_kernel<0,0><<<gFull, blk, 0, stream>>>(query, Wq,  bq,  q,  EE, EE, sc,  ST, -1);
    gemm_kernel<0,0><<<gFull, blk, 0, stream>>>(query, Wk,  bk,  k,  EE, EE, 1.f, ST, -1);
    gemm_kernel<0,0><<<gFull, blk, 0, stream>>>(query, Wv,  bv,  v,  EE, EE, 1.f, ST, -1);
    gemm_kernel<0,0><<<gFull, blk, 0, stream>>>(query, Wkg, bkg, kg, EE, EE, 1.f, ST, -1);
    gemm_kernel<0,0><<<gFull, blk, 0, stream>>>(query, Wvg, bvg, vg, EE, EE, 1.f, ST, -1);
    gemm_kernel<0,0><<<gQg,   blk, 0, stream>>>(query, Wqg, bqg, qg, EE, EE, sc,  SG, -1);

    band_attn_kernel<<<BBATCH * HH * (TT / 64), blk, 0, stream>>>(q, k, v, attnb);
    global_attn_kernel<<<BBATCH * HH * GG, blk, 0, stream>>>(qg, kg, vg, attnb);

    gemm_kernel<1,1><<<gFull, blk, 0, stream>>>(attnb, Wo, bo, (void*)d_out, EE, EE, 1.f, -1, ST);
}

// Round 4
// 565.623 us; speedup vs baseline: 5.0676x; 2.0027x over previous
//
#include <hip/hip_runtime.h>
#include <hip/hip_bf16.h>

typedef unsigned short u16;
typedef __bf16 bf16x8 __attribute__((ext_vector_type(8)));
typedef float  f32x4  __attribute__((ext_vector_type(4)));

constexpr int TT = 4096;   // seq
constexpr int BBATCH = 2;  // batch
constexpr int EE = 1024;   // embed
constexpr int HH = 16;     // heads
constexpr int DD = 64;     // head dim
constexpr int WQ = 256;    // one-sided window
constexpr int GG = 64;     // global tokens
constexpr int NSPLIT = 8;  // key splits for global attention

// ---------- bf16 helpers ----------
__device__ __forceinline__ float bf2f(u16 u) {
    union { unsigned int i; float f; } c; c.i = ((unsigned int)u) << 16; return c.f;
}
__device__ __forceinline__ u16 f2bf(float f) {
    union { float f; unsigned int i; } c; c.f = f;
    unsigned int x = c.i;
    return (u16)((x + 0x7fffu + ((x >> 16) & 1u)) >> 16);  // RNE
}
__device__ __forceinline__ uint4 pack8(float4 a, float4 b) {
    uint4 r;
    r.x = (unsigned)f2bf(a.x) | ((unsigned)f2bf(a.y) << 16);
    r.y = (unsigned)f2bf(a.z) | ((unsigned)f2bf(a.w) << 16);
    r.z = (unsigned)f2bf(b.x) | ((unsigned)f2bf(b.y) << 16);
    r.w = (unsigned)f2bf(b.z) | ((unsigned)f2bf(b.w) << 16);
    return r;
}

// ---------- GEMM: C = (A @ W^T + bias) * scale ---------- (unchanged, passing)
template<int A_BF16, int C_F32>
__global__ __launch_bounds__(256) void gemm_kernel(
    const void* __restrict__ Av, const float* __restrict__ W,
    const float* __restrict__ bias, void* __restrict__ Cv,
    int N, int K, float scale, int permA_S, int permC_S)
{
    const int tid  = threadIdx.x;
    const int lane = tid & 63;
    const int wave = tid >> 6;
    const int wm = wave >> 1, wn = wave & 1;
    const int m0 = blockIdx.y << 7, n0 = blockIdx.x << 7;

    __shared__ __align__(16) u16 As[128][40];
    __shared__ __align__(16) u16 Bs[128][40];

    const int srow = tid >> 2;
    const int scol = (tid & 3) << 3;
    auto mapr = [](int r, int s) -> size_t {
        return (s >= 0) ? (size_t)((r & ((1 << s) - 1)) * BBATCH + (r >> s)) : (size_t)r;
    };
    const size_t ar0 = mapr(m0 + srow, permA_S), ar1 = mapr(m0 + srow + 64, permA_S);
    const u16*   aB0 = (const u16*)Av + ar0 * K + scol;
    const u16*   aB1 = (const u16*)Av + ar1 * K + scol;
    const float* aF0 = (const float*)Av + ar0 * K + scol;
    const float* aF1 = (const float*)Av + ar1 * K + scol;
    const float* wF0 = W + (size_t)(n0 + srow) * K + scol;
    const float* wF1 = wF0 + (size_t)64 * K;
    u16* ldsA0 = &As[srow][scol];
    u16* ldsA1 = &As[srow + 64][scol];
    u16* ldsB0 = &Bs[srow][scol];
    u16* ldsB1 = &Bs[srow + 64][scol];

    f32x4 acc[4][4];
#pragma unroll
    for (int i = 0; i < 4; i++)
#pragma unroll
        for (int j = 0; j < 4; j++)
            acc[i][j] = (f32x4){0.f, 0.f, 0.f, 0.f};

    const int fr = lane & 15;
    const int fq = (lane >> 4) << 3;

    for (int k0 = 0; k0 < K; k0 += 32) {
        uint4 a0, a1;
        if (A_BF16) {
            a0 = *(const uint4*)(aB0 + k0);
            a1 = *(const uint4*)(aB1 + k0);
        } else {
            a0 = pack8(*(const float4*)(aF0 + k0), *(const float4*)(aF0 + k0 + 4));
            a1 = pack8(*(const float4*)(aF1 + k0), *(const float4*)(aF1 + k0 + 4));
        }
        const uint4 b0 = pack8(*(const float4*)(wF0 + k0), *(const float4*)(wF0 + k0 + 4));
        const uint4 b1 = pack8(*(const float4*)(wF1 + k0), *(const float4*)(wF1 + k0 + 4));
        *(uint4*)ldsA0 = a0;
        *(uint4*)ldsA1 = a1;
        *(uint4*)ldsB0 = b0;
        *(uint4*)ldsB1 = b1;
        __syncthreads();
        bf16x8 af[4], bfv[4];
#pragma unroll
        for (int i = 0; i < 4; i++)
            af[i] = *(const bf16x8*)&As[(wm << 6) + (i << 4) + fr][fq];
#pragma unroll
        for (int j = 0; j < 4; j++)
            bfv[j] = *(const bf16x8*)&Bs[(wn << 6) + (j << 4) + fr][fq];
#pragma unroll
        for (int i = 0; i < 4; i++)
#pragma unroll
            for (int j = 0; j < 4; j++)
                acc[i][j] = __builtin_amdgcn_mfma_f32_16x16x32_bf16(af[i], bfv[j], acc[i][j], 0, 0, 0);
        __syncthreads();
    }

    const int colbase = n0 + (wn << 6);
    const int rowbase = m0 + (wm << 6) + ((lane >> 4) << 2);
#pragma unroll
    for (int j = 0; j < 4; j++) {
        const int col = colbase + (j << 4) + fr;
        const float bv = bias[col];
#pragma unroll
        for (int i = 0; i < 4; i++) {
#pragma unroll
            for (int r = 0; r < 4; r++) {
                const int row = rowbase + (i << 4) + r;
                const float val = (acc[i][j][r] + bv) * scale;
                const size_t dst = mapr(row, permC_S) * N + col;
                if (C_F32) ((float*)Cv)[dst] = val;
                else       ((u16*)Cv)[dst]   = f2bf(val);
            }
        }
    }
}

// ---------- band attention, MFMA flash style ---------- (unchanged, passing)
__global__ __launch_bounds__(256) void band_attn_kernel(
    const u16* __restrict__ q, const u16* __restrict__ k, const u16* __restrict__ v,
    u16* __restrict__ attnb)
{
    const int tid  = threadIdx.x;
    const int lane = tid & 63;
    const int w    = tid >> 6;
    const int col  = lane & 15;
    const int quad = lane >> 4;

    const int qt = blockIdx.x & 63;
    const int h  = (blockIdx.x >> 6) & (HH - 1);
    const int b  = blockIdx.x >> 10;
    const int t0 = qt << 6;

    __shared__ __align__(16) u16 Qs[64][72];
    __shared__ __align__(16) u16 Ks[64][72];
    __shared__ __align__(16) u16 Vs[64][70];
    __shared__ __align__(16) u16 Ps[4][16][72];

    const size_t base = (size_t)b * TT * EE + (size_t)h * DD;

    {
        const int qr   = tid >> 2;
        const int part = (tid & 3) << 4;
        const uint4* src = (const uint4*)(q + base + (size_t)(t0 + qr) * EE + part);
        *(uint4*)&Qs[qr][part]     = src[0];
        *(uint4*)&Qs[qr][part + 8] = src[1];
    }

    float m_i[4], l_i[4];
    f32x4 acc_o[4];
#pragma unroll
    for (int r = 0; r < 4; r++) { m_i[r] = -1e30f; l_i[r] = 0.f; }
#pragma unroll
    for (int nt = 0; nt < 4; nt++) acc_o[nt] = (f32x4){0.f, 0.f, 0.f, 0.f};

#pragma unroll 1
    for (int cc = 0; cc < 10; cc++) {
        {
            const int kk   = tid >> 2;
            const int part = (tid & 3) << 4;
            int pos = (cc == 0) ? kk : (t0 - WQ + ((cc - 1) << 6) + kk);
            pos = pos < 0 ? 0 : (pos > TT - 1 ? TT - 1 : pos);
            const uint4* ks = (const uint4*)(k + base + (size_t)pos * EE + part);
            const uint4* vs = (const uint4*)(v + base + (size_t)pos * EE + part);
            const uint4 k0v = ks[0], k1v = ks[1];
            const uint4 v0v = vs[0], v1v = vs[1];
            *(uint4*)&Ks[kk][part]     = k0v;
            *(uint4*)&Ks[kk][part + 8] = k1v;
            unsigned int* vd = (unsigned int*)&Vs[kk][part];
            vd[0] = v0v.x; vd[1] = v0v.y; vd[2] = v0v.z; vd[3] = v0v.w;
            vd[4] = v1v.x; vd[5] = v1v.y; vd[6] = v1v.z; vd[7] = v1v.w;
        }
        __syncthreads();

        bf16x8 qf0 = *(const bf16x8*)&Qs[(w << 4) + col][quad << 3];
        bf16x8 qf1 = *(const bf16x8*)&Qs[(w << 4) + col][32 + (quad << 3)];
        f32x4 acc_s[4];
#pragma unroll
        for (int nt = 0; nt < 4; nt++) {
            bf16x8 kf0 = *(const bf16x8*)&Ks[(nt << 4) + col][quad << 3];
            bf16x8 kf1 = *(const bf16x8*)&Ks[(nt << 4) + col][32 + (quad << 3)];
            f32x4 s = (f32x4){0.f, 0.f, 0.f, 0.f};
            s = __builtin_amdgcn_mfma_f32_16x16x32_bf16(qf0, kf0, s, 0, 0, 0);
            s = __builtin_amdgcn_mfma_f32_16x16x32_bf16(qf1, kf1, s, 0, 0, 0);
            acc_s[nt] = s;
        }

        if (cc > 0) {
            const int kj0 = (cc - 1) << 6;
#pragma unroll
            for (int nt = 0; nt < 4; nt++) {
#pragma unroll
                for (int r = 0; r < 4; r++) {
                    const int jp   = kj0 + (nt << 4) + col;
                    const int qrow = (w << 4) + (quad << 2) + r;
                    const int pos  = t0 - WQ + jp;
                    const bool ok  = (jp >= qrow) && (jp - qrow <= 2 * WQ) &&
                                     (pos >= 0) && (pos < TT);
                    if (!ok) acc_s[nt][r] = -1e30f;
                }
            }
        }

        float m_c[4], p_sum[4];
#pragma unroll
        for (int r = 0; r < 4; r++) {
            float mx = fmaxf(fmaxf(acc_s[0][r], acc_s[1][r]), fmaxf(acc_s[2][r], acc_s[3][r]));
#pragma unroll
            for (int off = 1; off < 16; off <<= 1) mx = fmaxf(mx, __shfl_xor(mx, off));
            m_c[r] = mx;
        }
#pragma unroll
        for (int r = 0; r < 4; r++) {
            const float m_new = fmaxf(m_i[r], m_c[r]);
            const float alpha = __expf(m_i[r] - m_new);
            m_i[r] = m_new;
            l_i[r] *= alpha;
#pragma unroll
            for (int nt = 0; nt < 4; nt++) acc_o[nt][r] *= alpha;
            float ps = 0.f;
#pragma unroll
            for (int nt = 0; nt < 4; nt++) {
                const float e = __expf(acc_s[nt][r] - m_new);
                acc_s[nt][r] = e;
                ps += e;
            }
            p_sum[r] = ps;
        }
#pragma unroll
        for (int r = 0; r < 4; r++) {
            float ps = p_sum[r];
#pragma unroll
            for (int off = 1; off < 16; off <<= 1) ps += __shfl_xor(ps, off);
            l_i[r] += ps;
        }

#pragma unroll
        for (int nt = 0; nt < 4; nt++)
#pragma unroll
            for (int r = 0; r < 4; r++)
                Ps[w][(quad << 2) + r][(nt << 4) + col] = f2bf(acc_s[nt][r]);

        bf16x8 pf0 = *(const bf16x8*)&Ps[w][col][quad << 3];
        bf16x8 pf1 = *(const bf16x8*)&Ps[w][col][32 + (quad << 3)];
#pragma unroll
        for (int nt = 0; nt < 4; nt++) {
            union { bf16x8 v; u16 e[8]; } vf0, vf1;
#pragma unroll
            for (int j = 0; j < 8; j++) {
                vf0.e[j] = Vs[(quad << 3) + j][(nt << 4) + col];
                vf1.e[j] = Vs[32 + (quad << 3) + j][(nt << 4) + col];
            }
            acc_o[nt] = __builtin_amdgcn_mfma_f32_16x16x32_bf16(pf0, vf0.v, acc_o[nt], 0, 0, 0);
            acc_o[nt] = __builtin_amdgcn_mfma_f32_16x16x32_bf16(pf1, vf1.v, acc_o[nt], 0, 0, 0);
        }
        __syncthreads();
    }

    float inv[4];
#pragma unroll
    for (int r = 0; r < 4; r++) inv[r] = 1.f / l_i[r];
#pragma unroll
    for (int nt = 0; nt < 4; nt++) {
#pragma unroll
        for (int r = 0; r < 4; r++) {
            const int t = t0 + (w << 4) + (quad << 2) + r;
            attnb[base + (size_t)t * EE + (nt << 4) + col] = f2bf(acc_o[nt][r] * inv[r]);
        }
    }
}

// ---------- global-token attention, MFMA flash + split-K ----------
// Block (b,h,s): 64 global queries vs key slab [s*512,(s+1)*512), 8 chunks of 64.
// Writes unnormalized fp32 O partial + per-row (m,l). blockIdx.x = (b*H+h)*NSPLIT + s.
__global__ __launch_bounds__(256) void global_attn_flash_kernel(
    const u16* __restrict__ qg, const u16* __restrict__ kg, const u16* __restrict__ vg,
    float* __restrict__ Op, float* __restrict__ Ml, float* __restrict__ Ll)
{
    const int tid  = threadIdx.x;
    const int lane = tid & 63;
    const int w    = tid >> 6;
    const int col  = lane & 15;
    const int quad = lane >> 4;

    const int s  = blockIdx.x & (NSPLIT - 1);
    const int h  = (blockIdx.x >> 3) & (HH - 1);
    const int b  = blockIdx.x >> 7;
    const int k0pos = s * (TT / NSPLIT);

    __shared__ __align__(16) u16 Qs[64][72];
    __shared__ __align__(16) u16 Ks[64][72];
    __shared__ __align__(16) u16 Vs[64][70];
    __shared__ __align__(16) u16 Ps[4][16][72];

    const size_t base = (size_t)b * TT * EE + (size_t)h * DD;

    // stage Q tile: qg is [B*G, E], row b*G+g
    {
        const int qr   = tid >> 2;
        const int part = (tid & 3) << 4;
        const uint4* src = (const uint4*)(qg + (size_t)(b * GG + qr) * EE + (size_t)h * DD + part);
        *(uint4*)&Qs[qr][part]     = src[0];
        *(uint4*)&Qs[qr][part + 8] = src[1];
    }

    float m_i[4], l_i[4];
    f32x4 acc_o[4];
#pragma unroll
    for (int r = 0; r < 4; r++) { m_i[r] = -1e30f; l_i[r] = 0.f; }
#pragma unroll
    for (int nt = 0; nt < 4; nt++) acc_o[nt] = (f32x4){0.f, 0.f, 0.f, 0.f};

#pragma unroll 1
    for (int cc = 0; cc < TT / NSPLIT / 64; cc++) {
        {
            const int kk   = tid >> 2;
            const int part = (tid & 3) << 4;
            const int pos  = k0pos + (cc << 6) + kk;
            const uint4* ks = (const uint4*)(kg + base + (size_t)pos * EE + part);
            const uint4* vs = (const uint4*)(vg + base + (size_t)pos * EE + part);
            const uint4 k0v = ks[0], k1v = ks[1];
            const uint4 v0v = vs[0], v1v = vs[1];
            *(uint4*)&Ks[kk][part]     = k0v;
            *(uint4*)&Ks[kk][part + 8] = k1v;
            unsigned int* vd = (unsigned int*)&Vs[kk][part];
            vd[0] = v0v.x; vd[1] = v0v.y; vd[2] = v0v.z; vd[3] = v0v.w;
            vd[4] = v1v.x; vd[5] = v1v.y; vd[6] = v1v.z; vd[7] = v1v.w;
        }
        __syncthreads();

        bf16x8 qf0 = *(const bf16x8*)&Qs[(w << 4) + col][quad << 3];
        bf16x8 qf1 = *(const bf16x8*)&Qs[(w << 4) + col][32 + (quad << 3)];
        f32x4 acc_s[4];
#pragma unroll
        for (int nt = 0; nt < 4; nt++) {
            bf16x8 kf0 = *(const bf16x8*)&Ks[(nt << 4) + col][quad << 3];
            bf16x8 kf1 = *(const bf16x8*)&Ks[(nt << 4) + col][32 + (quad << 3)];
            f32x4 sv = (f32x4){0.f, 0.f, 0.f, 0.f};
            sv = __builtin_amdgcn_mfma_f32_16x16x32_bf16(qf0, kf0, sv, 0, 0, 0);
            sv = __builtin_amdgcn_mfma_f32_16x16x32_bf16(qf1, kf1, sv, 0, 0, 0);
            acc_s[nt] = sv;
        }

        float m_c[4], p_sum[4];
#pragma unroll
        for (int r = 0; r < 4; r++) {
            float mx = fmaxf(fmaxf(acc_s[0][r], acc_s[1][r]), fmaxf(acc_s[2][r], acc_s[3][r]));
#pragma unroll
            for (int off = 1; off < 16; off <<= 1) mx = fmaxf(mx, __shfl_xor(mx, off));
            m_c[r] = mx;
        }
#pragma unroll
        for (int r = 0; r < 4; r++) {
            const float m_new = fmaxf(m_i[r], m_c[r]);
            const float alpha = __expf(m_i[r] - m_new);
            m_i[r] = m_new;
            l_i[r] *= alpha;
#pragma unroll
            for (int nt = 0; nt < 4; nt++) acc_o[nt][r] *= alpha;
            float ps = 0.f;
#pragma unroll
            for (int nt = 0; nt < 4; nt++) {
                const float e = __expf(acc_s[nt][r] - m_new);
                acc_s[nt][r] = e;
                ps += e;
            }
            p_sum[r] = ps;
        }
#pragma unroll
        for (int r = 0; r < 4; r++) {
            float ps = p_sum[r];
#pragma unroll
            for (int off = 1; off < 16; off <<= 1) ps += __shfl_xor(ps, off);
            l_i[r] += ps;
        }

#pragma unroll
        for (int nt = 0; nt < 4; nt++)
#pragma unroll
            for (int r = 0; r < 4; r++)
                Ps[w][(quad << 2) + r][(nt << 4) + col] = f2bf(acc_s[nt][r]);

        bf16x8 pf0 = *(const bf16x8*)&Ps[w][col][quad << 3];
        bf16x8 pf1 = *(const bf16x8*)&Ps[w][col][32 + (quad << 3)];
#pragma unroll
        for (int nt = 0; nt < 4; nt++) {
            union { bf16x8 v; u16 e[8]; } vf0, vf1;
#pragma unroll
            for (int j = 0; j < 8; j++) {
                vf0.e[j] = Vs[(quad << 3) + j][(nt << 4) + col];
                vf1.e[j] = Vs[32 + (quad << 3) + j][(nt << 4) + col];
            }
            acc_o[nt] = __builtin_amdgcn_mfma_f32_16x16x32_bf16(pf0, vf0.v, acc_o[nt], 0, 0, 0);
            acc_o[nt] = __builtin_amdgcn_mfma_f32_16x16x32_bf16(pf1, vf1.v, acc_o[nt], 0, 0, 0);
        }
        __syncthreads();
    }

    // store partials: Op[blk][row][dim] fp32 unnormalized; Ml/Ll[blk][row]
    const size_t obase = (size_t)blockIdx.x * GG * DD;
#pragma unroll
    for (int nt = 0; nt < 4; nt++) {
#pragma unroll
        for (int r = 0; r < 4; r++) {
            const int row = (w << 4) + (quad << 2) + r;
            Op[obase + (size_t)row * DD + (nt << 4) + col] = acc_o[nt][r];
        }
    }
    if (col == 0) {
#pragma unroll
        for (int r = 0; r < 4; r++) {
            const int row = (w << 4) + (quad << 2) + r;
            Ml[blockIdx.x * GG + row] = m_i[r];
            Ll[blockIdx.x * GG + row] = l_i[r];
        }
    }
}

// ---------- combine split-K partials -> attnb rows [0,G) ----------
// one block per (b,h); thread = (row g = tid>>2, 16-dim group d0 = (tid&3)*16)
__global__ __launch_bounds__(256) void global_combine_kernel(
    const float* __restrict__ Op, const float* __restrict__ Ml, const float* __restrict__ Ll,
    u16* __restrict__ attnb)
{
    const int bh  = blockIdx.x;          // b*H + h
    const int b   = bh >> 4;
    const int h   = bh & (HH - 1);
    const int row = threadIdx.x >> 2;
    const int d0  = (threadIdx.x & 3) << 4;

    float mv[NSPLIT];
    float m = -1e30f;
#pragma unroll
    for (int s = 0; s < NSPLIT; s++) {
        mv[s] = Ml[(bh * NSPLIT + s) * GG + row];
        m = fmaxf(m, mv[s]);
    }
    float l = 0.f;
    float sc[NSPLIT];
#pragma unroll
    for (int s = 0; s < NSPLIT; s++) {
        sc[s] = __expf(mv[s] - m);
        l += Ll[(bh * NSPLIT + s) * GG + row] * sc[s];
    }
    float o[16];
#pragma unroll
    for (int j = 0; j < 16; j++) o[j] = 0.f;
#pragma unroll
    for (int s = 0; s < NSPLIT; s++) {
        const float* src = Op + ((size_t)(bh * NSPLIT + s) * GG + row) * DD + d0;
        const float f = sc[s];
#pragma unroll
        for (int j = 0; j < 16; j += 4) {
            const float4 v4 = *(const float4*)(src + j);
            o[j + 0] = fmaf(v4.x, f, o[j + 0]);
            o[j + 1] = fmaf(v4.y, f, o[j + 1]);
            o[j + 2] = fmaf(v4.z, f, o[j + 2]);
            o[j + 3] = fmaf(v4.w, f, o[j + 3]);
        }
    }
    const float inv = 1.f / l;
    u16* dst = attnb + ((size_t)b * TT + row) * EE + (size_t)h * DD + d0;
#pragma unroll
    for (int j = 0; j < 16; j++) dst[j] = f2bf(o[j] * inv);
}

extern "C" void kernel_launch(void* const* d_in, const int* in_sizes, int n_in,
                              void* d_out, int out_size, void* d_ws, size_t ws_size,
                              hipStream_t stream)
{
    (void)in_sizes; (void)n_in; (void)out_size; (void)ws_size;
    const float* query = (const float*)d_in[0];
    const float* Wq  = (const float*)d_in[2];  const float* bq  = (const float*)d_in[3];
    const float* Wk  = (const float*)d_in[4];  const float* bk  = (const float*)d_in[5];
    const float* Wv  = (const float*)d_in[6];  const float* bv  = (const float*)d_in[7];
    const float* Wqg = (const float*)d_in[8];  const float* bqg = (const float*)d_in[9];
    const float* Wkg = (const float*)d_in[10]; const float* bkg = (const float*)d_in[11];
    const float* Wvg = (const float*)d_in[12]; const float* bvg = (const float*)d_in[13];
    const float* Wo  = (const float*)d_in[14]; const float* bo  = (const float*)d_in[15];

    const size_t nfull = (size_t)BBATCH * TT * EE;
    u16* q     = (u16*)d_ws;
    u16* k     = q  + nfull;
    u16* v     = k  + nfull;
    u16* kg    = v  + nfull;
    u16* vg    = kg + nfull;
    u16* qg    = vg + nfull;
    u16* attnb = qg + (size_t)BBATCH * GG * EE;
    float* Op  = (float*)(attnb + nfull);                       // [B*H*NSPLIT][G][D] fp32
    float* Ml  = Op + (size_t)BBATCH * HH * NSPLIT * GG * DD;   // [B*H*NSPLIT][G]
    float* Ll  = Ml + (size_t)BBATCH * HH * NSPLIT * GG;
    // ws total ≈ 101 MB

    const dim3 blk(256);
    const dim3 gFull(EE / 128, (BBATCH * TT) / 128);
    const dim3 gQg(EE / 128, (BBATCH * GG) / 128);
    const float sc = 0.125f;  // D^-0.5
    const int ST = 12;
    const int SG = 6;

    gemm_kernel<0,0><<<gFull, blk, 0, stream>>>(query, Wq,  bq,  q,  EE, EE, sc,  ST, -1);
    gemm_kernel<0,0><<<gFull, blk, 0, stream>>>(query, Wk,  bk,  k,  EE, EE, 1.f, ST, -1);
    gemm_kernel<0,0><<<gFull, blk, 0, stream>>>(query, Wv,  bv,  v,  EE, EE, 1.f, ST, -1);
    gemm_kernel<0,0><<<gFull, blk, 0, stream>>>(query, Wkg, bkg, kg, EE, EE, 1.f, ST, -1);
    gemm_kernel<0,0><<<gFull, blk, 0, stream>>>(query, Wvg, bvg, vg, EE, EE, 1.f, ST, -1);
    gemm_kernel<0,0><<<gQg,   blk, 0, stream>>>(query, Wqg, bqg, qg, EE, EE, sc,  SG, -1);

    band_attn_kernel<<<BBATCH * HH * (TT / 64), blk, 0, stream>>>(q, k, v, attnb);
    global_attn_flash_kernel<<<BBATCH * HH * NSPLIT, blk, 0, stream>>>(qg, kg, vg, Op, Ml, Ll);
    global_combine_kernel<<<BBATCH * HH, blk, 0, stream>>>(Op, Ml, Ll, attnb);

    gemm_kernel<1,1><<<gFull, blk, 0, stream>>>(attnb, Wo, bo, (void*)d_out, EE, EE, 1.f, -1, ST);
}

// Round 5
// 430.278 us; speedup vs baseline: 6.6616x; 1.3146x over previous
//
#include <hip/hip_runtime.h>
#include <hip/hip_bf16.h>

typedef unsigned short u16;
typedef __bf16 bf16x8 __attribute__((ext_vector_type(8)));
typedef float  f32x4  __attribute__((ext_vector_type(4)));

constexpr int TT = 4096;   // seq
constexpr int BBATCH = 2;  // batch
constexpr int EE = 1024;   // embed
constexpr int HH = 16;     // heads
constexpr int DD = 64;     // head dim
constexpr int WQ = 256;    // one-sided window
constexpr int GG = 64;     // global tokens
constexpr int NSPLIT = 8;  // key splits for global attention

// ---------- bf16 helpers ----------
__device__ __forceinline__ float bf2f(u16 u) {
    union { unsigned int i; float f; } c; c.i = ((unsigned int)u) << 16; return c.f;
}
__device__ __forceinline__ u16 f2bf(float f) {
    union { float f; unsigned int i; } c; c.f = f;
    unsigned int x = c.i;
    return (u16)((x + 0x7fffu + ((x >> 16) & 1u)) >> 16);  // RNE
}
__device__ __forceinline__ uint4 pack8(float4 a, float4 b) {
    uint4 r;
    r.x = (unsigned)f2bf(a.x) | ((unsigned)f2bf(a.y) << 16);
    r.y = (unsigned)f2bf(a.z) | ((unsigned)f2bf(a.w) << 16);
    r.z = (unsigned)f2bf(b.x) | ((unsigned)f2bf(b.y) << 16);
    r.w = (unsigned)f2bf(b.z) | ((unsigned)f2bf(b.w) << 16);
    return r;
}
__device__ __forceinline__ float dot8(uint4 u, const float* qq) {
    union { unsigned int i; float f; } c;
    float s;
    c.i = u.x << 16;        s = qq[0] * c.f;
    c.i = u.x & 0xffff0000u; s = fmaf(qq[1], c.f, s);
    c.i = u.y << 16;        s = fmaf(qq[2], c.f, s);
    c.i = u.y & 0xffff0000u; s = fmaf(qq[3], c.f, s);
    c.i = u.z << 16;        s = fmaf(qq[4], c.f, s);
    c.i = u.z & 0xffff0000u; s = fmaf(qq[5], c.f, s);
    c.i = u.w << 16;        s = fmaf(qq[6], c.f, s);
    c.i = u.w & 0xffff0000u; s = fmaf(qq[7], c.f, s);
    return s;
}

// async global->LDS, 16B per lane; LDS dest = wave-uniform base + lane*16
__device__ __forceinline__ void g2l16(const u16* g, u16* l) {
    __builtin_amdgcn_global_load_lds(
        (const __attribute__((address_space(1))) void*)g,
        (__attribute__((address_space(3))) void*)l, 16, 0, 0);
}

// ---------- fp32 -> bf16 conversion: 7 weights (contiguous into wb) + query (perm [T,B,E]->[B,T,E]) ----------
struct WPtrs { const float* p[7]; };
__global__ __launch_bounds__(256) void conv_kernel(
    WPtrs wp, const float* __restrict__ query, u16* __restrict__ wb, u16* __restrict__ xb)
{
    const size_t i8 = ((size_t)blockIdx.x * 256 + threadIdx.x) << 3;
    const size_t WTOT = (size_t)7 << 20;   // 7 x 1024*1024
    const float* src;
    u16* dst;
    if (i8 < WTOT) {
        const int which = (int)(i8 >> 20);
        src = wp.p[which] + (i8 & (((size_t)1 << 20) - 1));
        dst = wb + i8;
    } else {
        const size_t j = i8 - WTOT;            // dst index in [B,T,E]
        const size_t e = j & (EE - 1);
        const size_t t = (j >> 10) & (TT - 1);
        const size_t b = j >> 22;
        src = query + (t * BBATCH + b) * EE + e;
        dst = xb + j;
    }
    const float4 f0 = *(const float4*)src;
    const float4 f1 = *(const float4*)(src + 4);
    *(uint4*)dst = pack8(f0, f1);
}

// ---------- GEMM (m97 structure): C = (A @ W^T + bias) * scale, A/W bf16, K=N=1024 ----------
// global_load_lds width-16 staging into unpadded [128][32] LDS; 16 MFMA + 8 ds_read_b128 per K-step.
// PERMA_QG: logical row m reads source row (m>>6)*4096 + (m&63)  (x[:, :G] gather, M=128)
// PERMC_TB: store row m=b*T+t to row t*2+b ([B,T]->[T,B])
template<int C_F32, int PERMA_QG, int PERMC_TB>
__global__ __launch_bounds__(256) void gemm_kernel(
    const u16* __restrict__ A, const u16* __restrict__ W, const float* __restrict__ bias,
    void* __restrict__ Cv, float scale)
{
    const int tid = threadIdx.x, lane = tid & 63, w = tid >> 6;
    const int wm = w >> 1, wn = w & 1;
    const int m0 = blockIdx.y << 7, n0 = blockIdx.x << 7;

    __shared__ __align__(16) u16 As[128 * 32];
    __shared__ __align__(16) u16 Bs[128 * 32];

    const int lrow = lane >> 2;            // 4 lanes per 64B row
    const int lcol = (lane & 3) << 3;
    auto arow = [](int m) -> size_t {
        return PERMA_QG ? (size_t)(((m >> 6) << 12) | (m & 63)) : (size_t)m;
    };
    const u16* gA0 = A + arow(m0 + (w << 4) + lrow) * EE + lcol;
    const u16* gA1 = A + arow(m0 + 64 + (w << 4) + lrow) * EE + lcol;
    const u16* gB0 = W + (size_t)(n0 + (w << 4) + lrow) * EE + lcol;
    const u16* gB1 = gB0 + (size_t)64 * EE;
    u16* lA0 = As + (w << 9);              // wave-uniform LDS bases (1024B apart)
    u16* lA1 = As + 2048 + (w << 9);
    u16* lB0 = Bs + (w << 9);
    u16* lB1 = Bs + 2048 + (w << 9);

    f32x4 acc[4][4];
#pragma unroll
    for (int i = 0; i < 4; i++)
#pragma unroll
        for (int j = 0; j < 4; j++)
            acc[i][j] = (f32x4){0.f, 0.f, 0.f, 0.f};

    const int fr = lane & 15;
    const int fq = (lane >> 4) << 3;

    for (int k0 = 0; k0 < EE; k0 += 32) {
        g2l16(gA0 + k0, lA0);
        g2l16(gA1 + k0, lA1);
        g2l16(gB0 + k0, lB0);
        g2l16(gB1 + k0, lB1);
        __syncthreads();                   // compiler drains vmcnt before s_barrier
        bf16x8 af[4], bfv[4];
#pragma unroll
        for (int i = 0; i < 4; i++)
            af[i] = *(const bf16x8*)&As[((wm << 6) + (i << 4) + fr) * 32 + fq];
#pragma unroll
        for (int j = 0; j < 4; j++)
            bfv[j] = *(const bf16x8*)&Bs[((wn << 6) + (j << 4) + fr) * 32 + fq];
#pragma unroll
        for (int i = 0; i < 4; i++)
#pragma unroll
            for (int j = 0; j < 4; j++)
                acc[i][j] = __builtin_amdgcn_mfma_f32_16x16x32_bf16(af[i], bfv[j], acc[i][j], 0, 0, 0);
        __syncthreads();
    }

    const int colbase = n0 + (wn << 6);
    const int rowbase = m0 + (wm << 6) + ((lane >> 4) << 2);
#pragma unroll
    for (int j = 0; j < 4; j++) {
        const int col = colbase + (j << 4) + fr;
        const float bv = bias[col];
#pragma unroll
        for (int i = 0; i < 4; i++) {
#pragma unroll
            for (int r = 0; r < 4; r++) {
                const int row = rowbase + (i << 4) + r;
                const float val = (acc[i][j][r] + bv) * scale;
                const size_t dst = (size_t)(PERMC_TB ? (((row & (TT - 1)) << 1) | (row >> 12)) : row) * EE + col;
                if (C_F32) ((float*)Cv)[dst] = val;
                else       ((u16*)Cv)[dst]   = f2bf(val);
            }
        }
    }
}

// ---------- band attention, MFMA flash style ----------
// blockIdx.x = qt*32 + (b*H+h): all 64 q-tiles of a (b,h) slab share blk%8 -> same XCD L2.
// V staged TRANSPOSED + XOR-swizzled: Vt[dim][ ((key>>3)^(dim&7))*8 + (key&7) ] -> PV B-frags are b128.
__global__ __launch_bounds__(256) void band_attn_kernel(
    const u16* __restrict__ q, const u16* __restrict__ k, const u16* __restrict__ v,
    u16* __restrict__ attnb)
{
    const int tid  = threadIdx.x;
    const int lane = tid & 63;
    const int w    = tid >> 6;
    const int col  = lane & 15;
    const int quad = lane >> 4;

    const int qt = blockIdx.x >> 5;
    const int bh = blockIdx.x & 31;
    const int h  = bh & (HH - 1);
    const int b  = bh >> 4;
    const int t0 = qt << 6;

    __shared__ __align__(16) u16 Qs[64][72];
    __shared__ __align__(16) u16 Ks[64][72];
    __shared__ __align__(16) u16 Vt[64][64];   // [dim][key swizzled]
    __shared__ __align__(16) u16 Ps[4][16][72];

    const size_t base = (size_t)b * TT * EE + (size_t)h * DD;

    {
        const int qr   = tid >> 2;
        const int part = (tid & 3) << 4;
        const uint4* src = (const uint4*)(q + base + (size_t)(t0 + qr) * EE + part);
        *(uint4*)&Qs[qr][part]     = src[0];
        *(uint4*)&Qs[qr][part + 8] = src[1];
    }

    float m_i[4], l_i[4];
    f32x4 acc_o[4];
#pragma unroll
    for (int r = 0; r < 4; r++) { m_i[r] = -1e30f; l_i[r] = 0.f; }
#pragma unroll
    for (int nt = 0; nt < 4; nt++) acc_o[nt] = (f32x4){0.f, 0.f, 0.f, 0.f};

#pragma unroll 1
    for (int cc = 0; cc < 10; cc++) {
        // ---- stage K (row-major) and V (transposed+swizzled) ----
        {
            const int kk   = tid >> 2;
            const int part = (tid & 3) << 4;
            int pos = (cc == 0) ? kk : (t0 - WQ + ((cc - 1) << 6) + kk);
            pos = pos < 0 ? 0 : (pos > TT - 1 ? TT - 1 : pos);
            const uint4* ks = (const uint4*)(k + base + (size_t)pos * EE + part);
            const uint4* vs = (const uint4*)(v + base + (size_t)pos * EE + part);
            const uint4 k0v = ks[0], k1v = ks[1];
            union { uint4 u[2]; u16 e[16]; } vu;
            vu.u[0] = vs[0]; vu.u[1] = vs[1];
            *(uint4*)&Ks[kk][part]     = k0v;
            *(uint4*)&Ks[kk][part + 8] = k1v;
            const int kblk = kk >> 3, kb = kk & 7;
#pragma unroll
            for (int j = 0; j < 16; j++) {
                const int d = part + j;
                Vt[d][((kblk ^ (d & 7)) << 3) | kb] = vu.e[j];
            }
        }
        __syncthreads();

        // ---- QK^T ----
        bf16x8 qf0 = *(const bf16x8*)&Qs[(w << 4) + col][quad << 3];
        bf16x8 qf1 = *(const bf16x8*)&Qs[(w << 4) + col][32 + (quad << 3)];
        f32x4 acc_s[4];
#pragma unroll
        for (int nt = 0; nt < 4; nt++) {
            bf16x8 kf0 = *(const bf16x8*)&Ks[(nt << 4) + col][quad << 3];
            bf16x8 kf1 = *(const bf16x8*)&Ks[(nt << 4) + col][32 + (quad << 3)];
            f32x4 s = (f32x4){0.f, 0.f, 0.f, 0.f};
            s = __builtin_amdgcn_mfma_f32_16x16x32_bf16(qf0, kf0, s, 0, 0, 0);
            s = __builtin_amdgcn_mfma_f32_16x16x32_bf16(qf1, kf1, s, 0, 0, 0);
            acc_s[nt] = s;
        }

        // ---- mask band chunks ----
        if (cc > 0) {
            const int kj0 = (cc - 1) << 6;
#pragma unroll
            for (int nt = 0; nt < 4; nt++) {
#pragma unroll
                for (int r = 0; r < 4; r++) {
                    const int jp   = kj0 + (nt << 4) + col;
                    const int qrow = (w << 4) + (quad << 2) + r;
                    const int pos  = t0 - WQ + jp;
                    const bool ok  = (jp >= qrow) && (jp - qrow <= 2 * WQ) &&
                                     (pos >= 0) && (pos < TT);
                    if (!ok) acc_s[nt][r] = -1e30f;
                }
            }
        }

        // ---- online softmax ----
        float m_c[4], p_sum[4];
#pragma unroll
        for (int r = 0; r < 4; r++) {
            float mx = fmaxf(fmaxf(acc_s[0][r], acc_s[1][r]), fmaxf(acc_s[2][r], acc_s[3][r]));
#pragma unroll
            for (int off = 1; off < 16; off <<= 1) mx = fmaxf(mx, __shfl_xor(mx, off));
            m_c[r] = mx;
        }
#pragma unroll
        for (int r = 0; r < 4; r++) {
            const float m_new = fmaxf(m_i[r], m_c[r]);
            const float alpha = __expf(m_i[r] - m_new);
            m_i[r] = m_new;
            l_i[r] *= alpha;
#pragma unroll
            for (int nt = 0; nt < 4; nt++) acc_o[nt][r] *= alpha;
            float ps = 0.f;
#pragma unroll
            for (int nt = 0; nt < 4; nt++) {
                const float e = __expf(acc_s[nt][r] - m_new);
                acc_s[nt][r] = e;
                ps += e;
            }
            p_sum[r] = ps;
        }
#pragma unroll
        for (int r = 0; r < 4; r++) {
            float ps = p_sum[r];
#pragma unroll
            for (int off = 1; off < 16; off <<= 1) ps += __shfl_xor(ps, off);
            l_i[r] += ps;
        }

        // ---- P: C-layout -> LDS (A-layout) ----
#pragma unroll
        for (int nt = 0; nt < 4; nt++)
#pragma unroll
            for (int r = 0; r < 4; r++)
                Ps[w][(quad << 2) + r][(nt << 4) + col] = f2bf(acc_s[nt][r]);

        // ---- PV via b128 reads from swizzled Vt ----
        bf16x8 pf0 = *(const bf16x8*)&Ps[w][col][quad << 3];
        bf16x8 pf1 = *(const bf16x8*)&Ps[w][col][32 + (quad << 3)];
        const int cx = col & 7;
#pragma unroll
        for (int nt = 0; nt < 4; nt++) {
            const int d = (nt << 4) + col;
            bf16x8 vf0 = *(const bf16x8*)&Vt[d][(quad ^ cx) << 3];
            bf16x8 vf1 = *(const bf16x8*)&Vt[d][((quad + 4) ^ cx) << 3];
            acc_o[nt] = __builtin_amdgcn_mfma_f32_16x16x32_bf16(pf0, vf0, acc_o[nt], 0, 0, 0);
            acc_o[nt] = __builtin_amdgcn_mfma_f32_16x16x32_bf16(pf1, vf1, acc_o[nt], 0, 0, 0);
        }
        __syncthreads();
    }

    float inv[4];
#pragma unroll
    for (int r = 0; r < 4; r++) inv[r] = 1.f / l_i[r];
#pragma unroll
    for (int nt = 0; nt < 4; nt++) {
#pragma unroll
        for (int r = 0; r < 4; r++) {
            const int t = t0 + (w << 4) + (quad << 2) + r;
            attnb[base + (size_t)t * EE + (nt << 4) + col] = f2bf(acc_o[nt][r] * inv[r]);
        }
    }
}

// ---------- global-token attention, MFMA flash + split-K ---------- (unchanged, passing)
__global__ __launch_bounds__(256) void global_attn_flash_kernel(
    const u16* __restrict__ qg, const u16* __restrict__ kg, const u16* __restrict__ vg,
    float* __restrict__ Op, float* __restrict__ Ml, float* __restrict__ Ll)
{
    const int tid  = threadIdx.x;
    const int lane = tid & 63;
    const int w    = tid >> 6;
    const int col  = lane & 15;
    const int quad = lane >> 4;

    const int s  = blockIdx.x & (NSPLIT - 1);
    const int h  = (blockIdx.x >> 3) & (HH - 1);
    const int b  = blockIdx.x >> 7;
    const int k0pos = s * (TT / NSPLIT);

    __shared__ __align__(16) u16 Qs[64][72];
    __shared__ __align__(16) u16 Ks[64][72];
    __shared__ __align__(16) u16 Vs[64][70];
    __shared__ __align__(16) u16 Ps[4][16][72];

    const size_t base = (size_t)b * TT * EE + (size_t)h * DD;

    {
        const int qr   = tid >> 2;
        const int part = (tid & 3) << 4;
        const uint4* src = (const uint4*)(qg + (size_t)(b * GG + qr) * EE + (size_t)h * DD + part);
        *(uint4*)&Qs[qr][part]     = src[0];
        *(uint4*)&Qs[qr][part + 8] = src[1];
    }

    float m_i[4], l_i[4];
    f32x4 acc_o[4];
#pragma unroll
    for (int r = 0; r < 4; r++) { m_i[r] = -1e30f; l_i[r] = 0.f; }
#pragma unroll
    for (int nt = 0; nt < 4; nt++) acc_o[nt] = (f32x4){0.f, 0.f, 0.f, 0.f};

#pragma unroll 1
    for (int cc = 0; cc < TT / NSPLIT / 64; cc++) {
        {
            const int kk   = tid >> 2;
            const int part = (tid & 3) << 4;
            const int pos  = k0pos + (cc << 6) + kk;
            const uint4* ks = (const uint4*)(kg + base + (size_t)pos * EE + part);
            const uint4* vs = (const uint4*)(vg + base + (size_t)pos * EE + part);
            const uint4 k0v = ks[0], k1v = ks[1];
            const uint4 v0v = vs[0], v1v = vs[1];
            *(uint4*)&Ks[kk][part]     = k0v;
            *(uint4*)&Ks[kk][part + 8] = k1v;
            unsigned int* vd = (unsigned int*)&Vs[kk][part];
            vd[0] = v0v.x; vd[1] = v0v.y; vd[2] = v0v.z; vd[3] = v0v.w;
            vd[4] = v1v.x; vd[5] = v1v.y; vd[6] = v1v.z; vd[7] = v1v.w;
        }
        __syncthreads();

        bf16x8 qf0 = *(const bf16x8*)&Qs[(w << 4) + col][quad << 3];
        bf16x8 qf1 = *(const bf16x8*)&Qs[(w << 4) + col][32 + (quad << 3)];
        f32x4 acc_s[4];
#pragma unroll
        for (int nt = 0; nt < 4; nt++) {
            bf16x8 kf0 = *(const bf16x8*)&Ks[(nt << 4) + col][quad << 3];
            bf16x8 kf1 = *(const bf16x8*)&Ks[(nt << 4) + col][32 + (quad << 3)];
            f32x4 sv = (f32x4){0.f, 0.f, 0.f, 0.f};
            sv = __builtin_amdgcn_mfma_f32_16x16x32_bf16(qf0, kf0, sv, 0, 0, 0);
            sv = __builtin_amdgcn_mfma_f32_16x16x32_bf16(qf1, kf1, sv, 0, 0, 0);
            acc_s[nt] = sv;
        }

        float m_c[4], p_sum[4];
#pragma unroll
        for (int r = 0; r < 4; r++) {
            float mx = fmaxf(fmaxf(acc_s[0][r], acc_s[1][r]), fmaxf(acc_s[2][r], acc_s[3][r]));
#pragma unroll
            for (int off = 1; off < 16; off <<= 1) mx = fmaxf(mx, __shfl_xor(mx, off));
            m_c[r] = mx;
        }
#pragma unroll
        for (int r = 0; r < 4; r++) {
            const float m_new = fmaxf(m_i[r], m_c[r]);
            const float alpha = __expf(m_i[r] - m_new);
            m_i[r] = m_new;
            l_i[r] *= alpha;
#pragma unroll
            for (int nt = 0; nt < 4; nt++) acc_o[nt][r] *= alpha;
            float ps = 0.f;
#pragma unroll
            for (int nt = 0; nt < 4; nt++) {
                const float e = __expf(acc_s[nt][r] - m_new);
                acc_s[nt][r] = e;
                ps += e;
            }
            p_sum[r] = ps;
        }
#pragma unroll
        for (int r = 0; r < 4; r++) {
            float ps = p_sum[r];
#pragma unroll
            for (int off = 1; off < 16; off <<= 1) ps += __shfl_xor(ps, off);
            l_i[r] += ps;
        }

#pragma unroll
        for (int nt = 0; nt < 4; nt++)
#pragma unroll
            for (int r = 0; r < 4; r++)
                Ps[w][(quad << 2) + r][(nt << 4) + col] = f2bf(acc_s[nt][r]);

        bf16x8 pf0 = *(const bf16x8*)&Ps[w][col][quad << 3];
        bf16x8 pf1 = *(const bf16x8*)&Ps[w][col][32 + (quad << 3)];
#pragma unroll
        for (int nt = 0; nt < 4; nt++) {
            union { bf16x8 v; u16 e[8]; } vf0, vf1;
#pragma unroll
            for (int j = 0; j < 8; j++) {
                vf0.e[j] = Vs[(quad << 3) + j][(nt << 4) + col];
                vf1.e[j] = Vs[32 + (quad << 3) + j][(nt << 4) + col];
            }
            acc_o[nt] = __builtin_amdgcn_mfma_f32_16x16x32_bf16(pf0, vf0.v, acc_o[nt], 0, 0, 0);
            acc_o[nt] = __builtin_amdgcn_mfma_f32_16x16x32_bf16(pf1, vf1.v, acc_o[nt], 0, 0, 0);
        }
        __syncthreads();
    }

    const size_t obase = (size_t)blockIdx.x * GG * DD;
#pragma unroll
    for (int nt = 0; nt < 4; nt++) {
#pragma unroll
        for (int r = 0; r < 4; r++) {
            const int row = (w << 4) + (quad << 2) + r;
            Op[obase + (size_t)row * DD + (nt << 4) + col] = acc_o[nt][r];
        }
    }
    if (col == 0) {
#pragma unroll
        for (int r = 0; r < 4; r++) {
            const int row = (w << 4) + (quad << 2) + r;
            Ml[blockIdx.x * GG + row] = m_i[r];
            Ll[blockIdx.x * GG + row] = l_i[r];
        }
    }
}

// ---------- combine split-K partials ---------- (unchanged, passing)
__global__ __launch_bounds__(256) void global_combine_kernel(
    const float* __restrict__ Op, const float* __restrict__ Ml, const float* __restrict__ Ll,
    u16* __restrict__ attnb)
{
    const int bh  = blockIdx.x;
    const int b   = bh >> 4;
    const int h   = bh & (HH - 1);
    const int row = threadIdx.x >> 2;
    const int d0  = (threadIdx.x & 3) << 4;

    float mv[NSPLIT];
    float m = -1e30f;
#pragma unroll
    for (int s = 0; s < NSPLIT; s++) {
        mv[s] = Ml[(bh * NSPLIT + s) * GG + row];
        m = fmaxf(m, mv[s]);
    }
    float l = 0.f;
    float sc[NSPLIT];
#pragma unroll
    for (int s = 0; s < NSPLIT; s++) {
        sc[s] = __expf(mv[s] - m);
        l += Ll[(bh * NSPLIT + s) * GG + row] * sc[s];
    }
    float o[16];
#pragma unroll
    for (int j = 0; j < 16; j++) o[j] = 0.f;
#pragma unroll
    for (int s = 0; s < NSPLIT; s++) {
        const float* src = Op + ((size_t)(bh * NSPLIT + s) * GG + row) * DD + d0;
        const float f = sc[s];
#pragma unroll
        for (int j = 0; j < 16; j += 4) {
            const float4 v4 = *(const float4*)(src + j);
            o[j + 0] = fmaf(v4.x, f, o[j + 0]);
            o[j + 1] = fmaf(v4.y, f, o[j + 1]);
            o[j + 2] = fmaf(v4.z, f, o[j + 2]);
            o[j + 3] = fmaf(v4.w, f, o[j + 3]);
        }
    }
    const float inv = 1.f / l;
    u16* dst = attnb + ((size_t)b * TT + row) * EE + (size_t)h * DD + d0;
#pragma unroll
    for (int j = 0; j < 16; j++) dst[j] = f2bf(o[j] * inv);
}

extern "C" void kernel_launch(void* const* d_in, const int* in_sizes, int n_in,
                              void* d_out, int out_size, void* d_ws, size_t ws_size,
                              hipStream_t stream)
{
    (void)in_sizes; (void)n_in; (void)out_size; (void)ws_size;
    const float* query = (const float*)d_in[0];
    const float* Wq  = (const float*)d_in[2];  const float* bq  = (const float*)d_in[3];
    const float* Wk  = (const float*)d_in[4];  const float* bk  = (const float*)d_in[5];
    const float* Wv  = (const float*)d_in[6];  const float* bv  = (const float*)d_in[7];
    const float* Wqg = (const float*)d_in[8];  const float* bqg = (const float*)d_in[9];
    const float* Wkg = (const float*)d_in[10]; const float* bkg = (const float*)d_in[11];
    const float* Wvg = (const float*)d_in[12]; const float* bvg = (const float*)d_in[13];
    const float* Wo  = (const float*)d_in[14]; const float* bo  = (const float*)d_in[15];

    const size_t nfull = (size_t)BBATCH * TT * EE;      // 8.39M elems
    const size_t wsz   = (size_t)1 << 20;               // one weight, elems
    u16* xb    = (u16*)d_ws;                            // bf16 x [B,T,E]; later reused as attnb
    u16* wb    = xb + nfull;                            // 7 converted weights
    u16* slotA = wb + 7 * wsz;                          // kg, then q
    u16* slotB = slotA + nfull;                         // vg, then k
    u16* slotC = slotB + nfull;                         // v
    u16* qg    = slotC + nfull;                         // [B*G, E]
    float* Op  = (float*)(qg + (size_t)BBATCH * GG * EE);
    float* Ml  = Op + (size_t)BBATCH * HH * NSPLIT * GG * DD;
    float* Ll  = Ml + (size_t)BBATCH * HH * NSPLIT * GG;
    u16* attnb = xb;                                    // alias: xb dead after last proj GEMM
    // peak ws ≈ 86 MB

    WPtrs wp;
    wp.p[0] = Wq; wp.p[1] = Wk; wp.p[2] = Wv; wp.p[3] = Wqg;
    wp.p[4] = Wkg; wp.p[5] = Wvg; wp.p[6] = Wo;

    const dim3 blk(256);
    const dim3 gFull(EE / 128, (BBATCH * TT) / 128);
    const dim3 gQg(EE / 128, 1);
    const float sc = 0.125f;  // D^-0.5

    conv_kernel<<<7680, blk, 0, stream>>>(wp, query, wb, xb);

    // global-path projections first, so their slots can be reused
    gemm_kernel<0,1,0><<<gQg,   blk, 0, stream>>>(xb, wb + 3 * wsz, bqg, qg,    sc);
    gemm_kernel<0,0,0><<<gFull, blk, 0, stream>>>(xb, wb + 4 * wsz, bkg, slotA, 1.f);
    gemm_kernel<0,0,0><<<gFull, blk, 0, stream>>>(xb, wb + 5 * wsz, bvg, slotB, 1.f);
    global_attn_flash_kernel<<<BBATCH * HH * NSPLIT, blk, 0, stream>>>(qg, slotA, slotB, Op, Ml, Ll);

    gemm_kernel<0,0,0><<<gFull, blk, 0, stream>>>(xb, wb + 0 * wsz, bq, slotA, sc);
    gemm_kernel<0,0,0><<<gFull, blk, 0, stream>>>(xb, wb + 1 * wsz, bk, slotB, 1.f);
    gemm_kernel<0,0,0><<<gFull, blk, 0, stream>>>(xb, wb + 2 * wsz, bv, slotC, 1.f);

    band_attn_kernel<<<BBATCH * HH * (TT / 64), blk, 0, stream>>>(slotA, slotB, slotC, attnb);
    global_combine_kernel<<<BBATCH * HH, blk, 0, stream>>>(Op, Ml, Ll, attnb);

    gemm_kernel<1,0,1><<<gFull, blk, 0, stream>>>(attnb, wb + 6 * wsz, bo, (void*)d_out, 1.f);
}